// Round 1
// 283.689 us; speedup vs baseline: 1.0317x; 1.0317x over previous
//
#include <hip/hip_runtime.h>

// irreps: 512x0e + 256x1o + 128x2e ; x,out: [16384, 1920] fp32, weight: 344064 fp32
// Strategy v2: ONE fused kernel. Per wg: stage the ENTIRE [TN x MUL*D] x-tile to LDS
// (fp32->bf16, d-deinterleaved, K-contiguous) in one coalesced pass, single barrier,
// then a barrier-free MFMA K-loop with B streamed from L2-resident bf16 weights.
// Barriers per wg: 32 -> 1. Segments interleaved 1:2:2 in one 2560-wg grid.

typedef float  f32x4  __attribute__((ext_vector_type(4)));
typedef short  bf16x8 __attribute__((ext_vector_type(8)));

#define ROWLEN 1920

__device__ __forceinline__ unsigned short f2bf(float f) {
    union { float f; unsigned int u; } c; c.f = f;
    unsigned int u = c.u;
    u += 0x7fffu + ((u >> 16) & 1u);   // round-to-nearest-even
    return (unsigned short)(u >> 16);
}

// weight blocks consecutive: [512*512][256*256][128*128] -> bf16 Wt[v][u], K-contiguous
__global__ __launch_bounds__(256) void prep_weights(const float* __restrict__ w,
                                                    unsigned short* __restrict__ wt) {
    int g = blockIdx.x * 256 + threadIdx.x;
    if (g >= 344064) return;
    int base, sh;
    if      (g < 262144) { base = 0;      sh = 9; }   // mul=512
    else if (g < 327680) { base = 262144; sh = 8; }   // mul=256
    else                 { base = 327680; sh = 7; }   // mul=128
    int local = g - base;
    int u = local >> sh;
    int v = local & ((1 << sh) - 1);
    wt[base + (v << sh) + u] = f2bf(w[g]);
}

// Logical GEMM: C[(n,i), v] = sum_u x[n,u,i] * W[u,v]
template<int MUL, int D, int TN, int X_OFF, int WT_BASE>
__device__ __forceinline__ void seg_body(const int bid,
                                         const float* __restrict__ x,
                                         const unsigned short* __restrict__ wt,
                                         float* __restrict__ out,
                                         const float scale,
                                         unsigned short* lds) {
    constexpr int KB      = 32;                 // K per MFMA step
    constexpr int NSTEP   = MUL / KB;
    constexpr int M_LOG   = TN * D;             // logical rows (mult of 16)
    constexpr int MT      = M_LOG / 16;
    constexpr int WAVE_NT = MUL / 64;           // 16-col tiles per wave
    constexpr int ST      = MUL + 8;            // shorts; stride_bytes%32==16 -> even bank spread
    constexpr int ROW_F4  = MUL * D / 4;        // f32x4 per x-row segment
    constexpr int ITERS   = TN * ROW_F4 / 256;  // exact for all three segs

    const int tid  = threadIdx.x;
    const int wave = tid >> 6;
    const int lane = tid & 63;
    const int q    = lane >> 4;
    const int t16  = lane & 15;
    const int n0   = bid * TN;

    const float* __restrict__ xblk = x + X_OFF + n0 * ROWLEN;

    // ---- stage FULL x-tile: contiguous fp32 -> bf16, de-interleave, K-contiguous LDS
#pragma unroll 4
    for (int it = 0; it < ITERS; ++it) {
        const int idx = tid + it * 256;
        const int nl  = idx / ROW_F4;            // const divisor -> magic mul
        const int c4  = (idx - nl * ROW_F4) * 4;
        const f32x4 vv = *(const f32x4*)(xblk + nl * ROWLEN + c4);
        if (D == 1) {
            unsigned int lo = (unsigned int)f2bf(vv[0]) | ((unsigned int)f2bf(vv[1]) << 16);
            unsigned int hi = (unsigned int)f2bf(vv[2]) | ((unsigned int)f2bf(vv[3]) << 16);
            unsigned int* p = (unsigned int*)&lds[nl * ST + c4];
            p[0] = lo; p[1] = hi;
        } else {
#pragma unroll
            for (int e = 0; e < 4; ++e) {
                const int c = c4 + e;
                const int u = c / D;             // const divisor -> magic mul
                const int i = c - u * D;
                lds[(i * TN + nl) * ST + u] = f2bf(vv[e]);
            }
        }
    }

    f32x4 acc[MT][WAVE_NT];
#pragma unroll
    for (int a = 0; a < MT; ++a)
#pragma unroll
        for (int b = 0; b < WAVE_NT; ++b) acc[a][b] = (f32x4)0.0f;

    __syncthreads();   // the ONLY barrier

    const unsigned short* __restrict__ wblk = wt + WT_BASE;
    const int vbase = wave * (WAVE_NT * 16) + t16;

    // ---- barrier-free K loop: A frags from LDS (ds_read_b128), B from L2-resident Wt
#pragma unroll 1
    for (int ks = 0; ks < NSTEP; ++ks) {
        bf16x8 afr[MT];
#pragma unroll
        for (int tm = 0; tm < MT; ++tm)
            afr[tm] = *(const bf16x8*)&lds[(16 * tm + t16) * ST + ks * KB + q * 8];
#pragma unroll
        for (int tv = 0; tv < WAVE_NT; ++tv) {
            const bf16x8 bfr = *(const bf16x8*)&wblk[(vbase + tv * 16) * MUL + ks * KB + q * 8];
#pragma unroll
            for (int tm = 0; tm < MT; ++tm)
                acc[tm][tv] = __builtin_amdgcn_mfma_f32_16x16x32_bf16(afr[tm], bfr, acc[tm][tv], 0, 0, 0);
        }
    }

    // ---- epilogue: C/D layout col=lane&15, row=q*4+r ; logical row -> (i, nl)
#pragma unroll
    for (int tm = 0; tm < MT; ++tm) {
#pragma unroll
        for (int tv = 0; tv < WAVE_NT; ++tv) {
            const int v = vbase + tv * 16;
#pragma unroll
            for (int r = 0; r < 4; ++r) {
                const int rit  = q * 4 + r;
                const int lrow = 16 * tm + rit;
                const int i    = lrow / TN;      // TN pow2 -> shift
                const int nl   = lrow - i * TN;
                out[(n0 + nl) * ROWLEN + X_OFF + v * D + i] = acc[tm][tv][r] * scale;
            }
        }
    }
}

// 2560 wgs: every 5 consecutive blocks = 1x seg0 + 2x seg1 + 2x seg2 (interleaved mix)
__global__ __launch_bounds__(256, 4) void fused_gemm(const float* __restrict__ x,
                                                     const unsigned short* __restrict__ wt,
                                                     float* __restrict__ out) {
    extern __shared__ unsigned short lds[];
    const int b = blockIdx.x;
    const int g = b / 5;
    const int r = b - g * 5;
    if (r == 0) {
        // seg0: mul=512, d=1, TN=32 -> 512 wgs, LDS 33280 B, per-wave 2x8 acc
        seg_body<512, 1, 32, 0, 0>(g, x, wt, out, 0.044194173824f, lds);
    } else if (r <= 2) {
        // seg1: mul=256, d=3, TN=16 -> 1024 wgs, LDS 25344 B, per-wave 3x4 acc
        seg_body<256, 3, 16, 512, 262144>(g * 2 + (r - 1), x, wt, out, 0.0625f, lds);
    } else {
        // seg2: mul=128, d=5, TN=16 -> 1024 wgs, LDS 21760 B, per-wave 5x2 acc
        seg_body<128, 5, 16, 1280, 327680>(g * 2 + (r - 3), x, wt, out, 0.088388347648f, lds);
    }
}

extern "C" void kernel_launch(void* const* d_in, const int* in_sizes, int n_in,
                              void* d_out, int out_size, void* d_ws, size_t ws_size,
                              hipStream_t stream) {
    const float* x = (const float*)d_in[0];
    const float* w = (const float*)d_in[1];
    float* out = (float*)d_out;
    unsigned short* wt = (unsigned short*)d_ws;   // 344064 bf16 = 688 KB, L2-resident

    hipLaunchKernelGGL(prep_weights, dim3((344064 + 255) / 256), dim3(256), 0, stream, w, wt);
    // dynamic LDS = max over segs = seg0's 32*520*2 = 33280 B -> 4 wgs/CU
    hipLaunchKernelGGL(fused_gemm, dim3(2560), dim3(256), 33280, stream, x, wt, out);
}

// Round 2
// 251.586 us; speedup vs baseline: 1.1633x; 1.1276x over previous
//
#include <hip/hip_runtime.h>

// irreps: 512x0e + 256x1o + 128x2e ; x,out: [16384, 1920] fp32, weight: 344064 fp32
// Strategy v3: fused kernel; per-wg full-K LDS staging (one barrier). Weights are
// pre-packed in MFMA FRAGMENT ORDER [v-tile][k-step][lane][8] so every B-load is one
// fully-coalesced 1KB wave-load. K-loop is software-pipelined: B(ks+1)/A(ks+1)
// prefetched into registers before MFMAs of step ks -> vmcnt never fully drains.

typedef float  f32x4  __attribute__((ext_vector_type(4)));
typedef short  bf16x8 __attribute__((ext_vector_type(8)));

#define ROWLEN 1920

__device__ __forceinline__ unsigned short f2bf(float f) {
    union { float f; unsigned int u; } c; c.f = f;
    unsigned int u = c.u;
    u += 0x7fffu + ((u >> 16) & 1u);   // round-to-nearest-even
    return (unsigned short)(u >> 16);
}

// Pack w (fp32, W[u][v] per segment, segments consecutive) into bf16 fragment order:
// frag element (vt, ks, lane, j) = W[ks*32 + (lane>>4)*8 + j][vt*16 + (lane&15)]
// stored at wt[seg_base + ((vt*NSTEP + ks)*64 + lane)*8 + j].
// One thread per 8 outputs -> 16B coalesced stores; scattered reads hit L2 (w = 1.4MB).
__global__ __launch_bounds__(256) void prep_weights(const float* __restrict__ w,
                                                    unsigned short* __restrict__ wt) {
    const int g = blockIdx.x * 256 + threadIdx.x;   // [0, 43008)
    if (g >= 43008) return;
    int t, base, mul, lognstep;
    if      (g < 32768) { t = g;         base = 0;      mul = 512; lognstep = 4; }
    else if (g < 40960) { t = g - 32768; base = 262144; mul = 256; lognstep = 3; }
    else                { t = g - 40960; base = 327680; mul = 128; lognstep = 2; }
    const int lane = t & 63;
    const int rest = t >> 6;
    const int ks   = rest & ((1 << lognstep) - 1);
    const int vt   = rest >> lognstep;
    const int v    = vt * 16 + (lane & 15);
    const int k0   = ks * 32 + (lane >> 4) * 8;
    const float* __restrict__ src = w + base + k0 * mul + v;
    bf16x8 vv;
#pragma unroll
    for (int j = 0; j < 8; ++j) vv[j] = (short)f2bf(src[j * mul]);
    *(bf16x8*)&wt[base + t * 8] = vv;
}

// Logical GEMM: C[(n,i), v] = sum_u x[n,u,i] * W[u,v]
template<int MUL, int D, int TN, int X_OFF, int WT_BASE>
__device__ __forceinline__ void seg_body(const int bid,
                                         const float* __restrict__ x,
                                         const unsigned short* __restrict__ wt,
                                         float* __restrict__ out,
                                         const float scale,
                                         unsigned short* lds) {
    constexpr int KB      = 32;                 // K per MFMA step
    constexpr int NSTEP   = MUL / KB;
    constexpr int M_LOG   = TN * D;             // logical rows (mult of 16)
    constexpr int MT      = M_LOG / 16;
    constexpr int WAVE_NT = MUL / 64;           // 16-col tiles per wave
    constexpr int ST      = MUL + 8;            // shorts; stride%32dw==4 -> 2-way (free)
    constexpr int ROW_F4  = MUL * D / 4;
    constexpr int ITERS   = TN * ROW_F4 / 256;  // exact for all three segs
    constexpr int TVS     = NSTEP * 512;        // shorts per v-tile in frag order

    const int tid  = threadIdx.x;
    const int wave = tid >> 6;
    const int lane = tid & 63;
    const int q    = lane >> 4;
    const int t16  = lane & 15;
    const int n0   = bid * TN;

    const float* __restrict__ xblk = x + X_OFF + n0 * ROWLEN;
    // per-lane fragment pointer: consecutive lanes -> consecutive 16B (coalesced)
    const unsigned short* __restrict__ wfrag =
        wt + WT_BASE + (wave * WAVE_NT) * TVS + lane * 8;

    f32x4 acc[MT][WAVE_NT];
#pragma unroll
    for (int a = 0; a < MT; ++a)
#pragma unroll
        for (int b = 0; b < WAVE_NT; ++b) acc[a][b] = (f32x4)0.0f;

    // ---- issue B(ks=0) loads before the barrier (independent of LDS)
    bf16x8 bfr[WAVE_NT];
#pragma unroll
    for (int tv = 0; tv < WAVE_NT; ++tv)
        bfr[tv] = *(const bf16x8*)&wfrag[tv * TVS];

    // ---- stage FULL x-tile: fp32 -> bf16, de-interleave, K-contiguous LDS
#pragma unroll
    for (int it = 0; it < ITERS; ++it) {
        const int idx = tid + it * 256;
        const int nl  = idx / ROW_F4;            // const divisor -> magic mul
        const int c4  = (idx - nl * ROW_F4) * 4;
        const f32x4 vv = *(const f32x4*)(xblk + nl * ROWLEN + c4);
        if (D == 1) {
            unsigned int lo = (unsigned int)f2bf(vv[0]) | ((unsigned int)f2bf(vv[1]) << 16);
            unsigned int hi = (unsigned int)f2bf(vv[2]) | ((unsigned int)f2bf(vv[3]) << 16);
            unsigned int* p = (unsigned int*)&lds[nl * ST + c4];
            p[0] = lo; p[1] = hi;
        } else {
#pragma unroll
            for (int e = 0; e < 4; ++e) {
                const int c = c4 + e;
                const int u = c / D;             // const divisor -> magic mul
                const int i = c - u * D;
                lds[(i * TN + nl) * ST + u] = f2bf(vv[e]);
            }
        }
    }

    __syncthreads();   // the ONLY barrier

    // ---- A(ks=0) fragments
    bf16x8 afr[MT];
#pragma unroll
    for (int tm = 0; tm < MT; ++tm)
        afr[tm] = *(const bf16x8*)&lds[(16 * tm + t16) * ST + q * 8];

    // ---- software-pipelined K loop: prefetch ks+1 before MFMAs of ks
#pragma unroll 2
    for (int ks = 0; ks < NSTEP - 1; ++ks) {
        bf16x8 bnx[WAVE_NT], anx[MT];
#pragma unroll
        for (int tv = 0; tv < WAVE_NT; ++tv)
            bnx[tv] = *(const bf16x8*)&wfrag[tv * TVS + (ks + 1) * 512];
#pragma unroll
        for (int tm = 0; tm < MT; ++tm)
            anx[tm] = *(const bf16x8*)&lds[(16 * tm + t16) * ST + (ks + 1) * KB + q * 8];
#pragma unroll
        for (int tv = 0; tv < WAVE_NT; ++tv)
#pragma unroll
            for (int tm = 0; tm < MT; ++tm)
                acc[tm][tv] = __builtin_amdgcn_mfma_f32_16x16x32_bf16(afr[tm], bfr[tv], acc[tm][tv], 0, 0, 0);
#pragma unroll
        for (int tv = 0; tv < WAVE_NT; ++tv) bfr[tv] = bnx[tv];
#pragma unroll
        for (int tm = 0; tm < MT; ++tm) afr[tm] = anx[tm];
    }
    // last step (no prefetch)
#pragma unroll
    for (int tv = 0; tv < WAVE_NT; ++tv)
#pragma unroll
        for (int tm = 0; tm < MT; ++tm)
            acc[tm][tv] = __builtin_amdgcn_mfma_f32_16x16x32_bf16(afr[tm], bfr[tv], acc[tm][tv], 0, 0, 0);

    // ---- epilogue: C/D layout col=lane&15, row=q*4+r ; logical row -> (i, nl)
#pragma unroll
    for (int tm = 0; tm < MT; ++tm) {
#pragma unroll
        for (int tv = 0; tv < WAVE_NT; ++tv) {
            const int v = wave * (WAVE_NT * 16) + t16 + tv * 16;
#pragma unroll
            for (int r = 0; r < 4; ++r) {
                const int rit  = q * 4 + r;
                const int lrow = 16 * tm + rit;
                const int i    = lrow / TN;      // TN pow2 -> shift
                const int nl   = lrow - i * TN;
                out[(n0 + nl) * ROWLEN + X_OFF + v * D + i] = acc[tm][tv][r] * scale;
            }
        }
    }
}

// 3072 wgs interleaved 1:1:1 (1024 each)
__global__ __launch_bounds__(256, 4) void fused_gemm(const float* __restrict__ x,
                                                     const unsigned short* __restrict__ wt,
                                                     float* __restrict__ out) {
    extern __shared__ unsigned short lds[];
    const int b = blockIdx.x;
    const int g = b / 3;
    const int r = b - g * 3;
    if (r == 0) {
        // seg0: mul=512, d=1, TN=16 -> LDS 16640 B, per-wave 1x8 acc
        seg_body<512, 1, 16, 0, 0>(g, x, wt, out, 0.044194173824f, lds);
    } else if (r == 1) {
        // seg1: mul=256, d=3, TN=16 -> LDS 25344 B, per-wave 3x4 acc
        seg_body<256, 3, 16, 512, 262144>(g, x, wt, out, 0.0625f, lds);
    } else {
        // seg2: mul=128, d=5, TN=16 -> LDS 21760 B, per-wave 5x2 acc
        seg_body<128, 5, 16, 1280, 327680>(g, x, wt, out, 0.088388347648f, lds);
    }
}

extern "C" void kernel_launch(void* const* d_in, const int* in_sizes, int n_in,
                              void* d_out, int out_size, void* d_ws, size_t ws_size,
                              hipStream_t stream) {
    const float* x = (const float*)d_in[0];
    const float* w = (const float*)d_in[1];
    float* out = (float*)d_out;
    unsigned short* wt = (unsigned short*)d_ws;   // 344064 bf16 = 688 KB, L2-resident

    hipLaunchKernelGGL(prep_weights, dim3(168), dim3(256), 0, stream, w, wt);
    // dynamic LDS = max over segs = seg1's 48*264*2 = 25344 B
    hipLaunchKernelGGL(fused_gemm, dim3(3072), dim3(256), 25344, stream, x, wt, out);
}

// Round 3
// 235.756 us; speedup vs baseline: 1.2414x; 1.0671x over previous
//
#include <hip/hip_runtime.h>

// irreps: 512x0e + 256x1o + 128x2e ; x,out: [16384, 1920] fp32, weight: 344064 fp32
// Strategy v4: fused kernel, 512-thread wgs (8 waves). Weights pre-packed in MFMA
// fragment order. seg1/seg2: ENTIRE B panel loaded to registers in one burst before
// staging -> K-loop is pure ds_read+MFMA (no global latency). seg0: depth-3 rotating
// register prefetch of B, fully unrolled (static indices). TN=32 for seg0 halves its
// L2 weight traffic. prep_weights: coalesced reads, scattered 2B stores, 1344 wgs.

typedef float  f32x4  __attribute__((ext_vector_type(4)));
typedef short  bf16x8 __attribute__((ext_vector_type(8)));

#define ROWLEN 1920

__device__ __forceinline__ unsigned short f2bf(float f) {
    union { float f; unsigned int u; } c; c.f = f;
    unsigned int u = c.u;
    u += 0x7fffu + ((u >> 16) & 1u);   // round-to-nearest-even
    return (unsigned short)(u >> 16);
}

// Fragment order: element (vt, ks, lane, j) = W[ks*32 + (lane>>4)*8 + j][vt*16 + (lane&15)]
// at wt[base + ((vt*NSTEP + ks)*64 + lane)*8 + j].  Coalesced READS of w, scattered stores.
__global__ __launch_bounds__(256) void prep_weights(const float* __restrict__ w,
                                                    unsigned short* __restrict__ wt) {
    const int g = blockIdx.x * 256 + threadIdx.x;
    if (g >= 344064) return;
    int base, lmul;
    if      (g < 262144) { base = 0;      lmul = 9; }   // mul=512
    else if (g < 327680) { base = 262144; lmul = 8; }   // mul=256
    else                 { base = 327680; lmul = 7; }   // mul=128
    const int local = g - base;
    const int u = local >> lmul;               // k index
    const int v = local & ((1 << lmul) - 1);   // output channel
    const int nstep_log = lmul - 5;            // NSTEP = mul/32
    const int vt   = v >> 4;
    const int ks   = u >> 5;
    const int lane = (((u >> 3) & 3) << 4) | (v & 15);
    const int j    = u & 7;
    wt[base + ((((vt << nstep_log) + ks) << 6) + lane) * 8 + j] = f2bf(w[g]);
}

// Logical GEMM: C[(n,i), v] = sum_u x[n,u,i] * W[u,v]
template<int MUL, int D, int TN, int X_OFF, int WT_BASE>
__device__ __forceinline__ void seg_body(const int bid,
                                         const float* __restrict__ x,
                                         const unsigned short* __restrict__ wt,
                                         float* __restrict__ out,
                                         const float scale,
                                         unsigned short* lds) {
    constexpr int KB      = 32;
    constexpr int NSTEP   = MUL / KB;
    constexpr int M_LOG   = TN * D;
    constexpr int MT      = M_LOG / 16;
    constexpr int NWAVE   = 8;
    constexpr int WAVE_NT = MUL / (NWAVE * 16);
    constexpr int ST      = MUL + 8;
    constexpr int ROW_F4  = MUL * D / 4;
    constexpr int ITERS   = TN * ROW_F4 / (NWAVE * 64);  // exact for all segs
    constexpr int TVS     = NSTEP * 512;                 // shorts per v-tile, frag order
    constexpr bool BREG   = (WAVE_NT * NSTEP) <= 16;     // full-B-in-regs <= 64 VGPR

    const int tid  = threadIdx.x;
    const int wave = tid >> 6;
    const int lane = tid & 63;
    const int q    = lane >> 4;
    const int t16  = lane & 15;
    const int n0   = bid * TN;

    const float* __restrict__ xblk = x + X_OFF + n0 * ROWLEN;
    const unsigned short* __restrict__ wfrag =
        wt + WT_BASE + (wave * WAVE_NT) * TVS + lane * 8;

    f32x4 acc[MT][WAVE_NT];
#pragma unroll
    for (int a = 0; a < MT; ++a)
#pragma unroll
        for (int b = 0; b < WAVE_NT; ++b) acc[a][b] = (f32x4)0.0f;

    auto stage_tile = [&]() {
#pragma unroll
        for (int it = 0; it < ITERS; ++it) {
            const int idx = tid + it * (NWAVE * 64);
            const int nl  = idx / ROW_F4;            // const divisor
            const int c4  = (idx - nl * ROW_F4) * 4;
            const f32x4 vv = *(const f32x4*)(xblk + nl * ROWLEN + c4);
            if (D == 1) {
                unsigned int lo = (unsigned int)f2bf(vv[0]) | ((unsigned int)f2bf(vv[1]) << 16);
                unsigned int hi = (unsigned int)f2bf(vv[2]) | ((unsigned int)f2bf(vv[3]) << 16);
                unsigned int* p = (unsigned int*)&lds[nl * ST + c4];
                p[0] = lo; p[1] = hi;
            } else {
#pragma unroll
                for (int e = 0; e < 4; ++e) {
                    const int c = c4 + e;
                    const int u = c / D;             // const divisor
                    const int i = c - u * D;
                    lds[(i * TN + nl) * ST + u] = f2bf(vv[e]);
                }
            }
        }
    };

    if constexpr (BREG) {
        // ---- burst-load the ENTIRE B panel into registers, then stage, one barrier
        bf16x8 breg[WAVE_NT * NSTEP];
#pragma unroll
        for (int tv = 0; tv < WAVE_NT; ++tv)
#pragma unroll
            for (int ks = 0; ks < NSTEP; ++ks)
                breg[tv * NSTEP + ks] = *(const bf16x8*)&wfrag[tv * TVS + ks * 512];
        stage_tile();
        __syncthreads();
        // ---- pure LDS+MFMA K-loop
#pragma unroll
        for (int ks = 0; ks < NSTEP; ++ks) {
            bf16x8 afr[MT];
#pragma unroll
            for (int tm = 0; tm < MT; ++tm)
                afr[tm] = *(const bf16x8*)&lds[(16 * tm + t16) * ST + ks * KB + q * 8];
#pragma unroll
            for (int tv = 0; tv < WAVE_NT; ++tv)
#pragma unroll
                for (int tm = 0; tm < MT; ++tm)
                    acc[tm][tv] = __builtin_amdgcn_mfma_f32_16x16x32_bf16(afr[tm], breg[tv * NSTEP + ks], acc[tm][tv], 0, 0, 0);
        }
    } else {
        // ---- streaming B with depth-3 rotating register prefetch (static indices)
        constexpr int PF = 3;
        bf16x8 bfr[4][WAVE_NT];
#pragma unroll
        for (int p = 0; p < PF; ++p)
#pragma unroll
            for (int tv = 0; tv < WAVE_NT; ++tv)
                bfr[p][tv] = *(const bf16x8*)&wfrag[tv * TVS + p * 512];
        stage_tile();
        __syncthreads();
#pragma unroll
        for (int ks = 0; ks < NSTEP; ++ks) {
            if (ks + PF < NSTEP) {
#pragma unroll
                for (int tv = 0; tv < WAVE_NT; ++tv)
                    bfr[(ks + PF) & 3][tv] = *(const bf16x8*)&wfrag[tv * TVS + (ks + PF) * 512];
            }
            bf16x8 afr[MT];
#pragma unroll
            for (int tm = 0; tm < MT; ++tm)
                afr[tm] = *(const bf16x8*)&lds[(16 * tm + t16) * ST + ks * KB + q * 8];
#pragma unroll
            for (int tv = 0; tv < WAVE_NT; ++tv)
#pragma unroll
                for (int tm = 0; tm < MT; ++tm)
                    acc[tm][tv] = __builtin_amdgcn_mfma_f32_16x16x32_bf16(afr[tm], bfr[ks & 3][tv], acc[tm][tv], 0, 0, 0);
        }
    }

    // ---- epilogue: C/D layout col=lane&15, row=q*4+r ; logical row -> (i, nl)
#pragma unroll
    for (int tm = 0; tm < MT; ++tm) {
#pragma unroll
        for (int tv = 0; tv < WAVE_NT; ++tv) {
            const int v = wave * (WAVE_NT * 16) + t16 + tv * 16;
#pragma unroll
            for (int r = 0; r < 4; ++r) {
                const int rit  = q * 4 + r;
                const int lrow = 16 * tm + rit;
                const int i    = lrow / TN;      // TN pow2 -> shift
                const int nl   = lrow - i * TN;
                out[(n0 + nl) * ROWLEN + X_OFF + v * D + i] = acc[tm][tv][r] * scale;
            }
        }
    }
}

// 2560 wgs, groups of 5: 1x seg0 + 2x seg1 + 2x seg2 (load-balanced interleave)
__global__ __launch_bounds__(512, 4) void fused_gemm(const float* __restrict__ x,
                                                     const unsigned short* __restrict__ wt,
                                                     float* __restrict__ out) {
    extern __shared__ unsigned short lds[];
    const int b = blockIdx.x;
    const int g = b / 5;
    const int r = b - g * 5;
    if (r == 0) {
        // seg0: mul=512, d=1, TN=32 -> 512 wgs, LDS 33280 B, stream-B depth-3
        seg_body<512, 1, 32, 0, 0>(g, x, wt, out, 0.044194173824f, lds);
    } else if (r <= 2) {
        // seg1: mul=256, d=3, TN=16 -> 1024 wgs, LDS 25344 B, B-in-regs (16 frags)
        seg_body<256, 3, 16, 512, 262144>(g * 2 + (r - 1), x, wt, out, 0.0625f, lds);
    } else {
        // seg2: mul=128, d=5, TN=16 -> 1024 wgs, LDS 21760 B, B-in-regs (4 frags)
        seg_body<128, 5, 16, 1280, 327680>(g * 2 + (r - 3), x, wt, out, 0.088388347648f, lds);
    }
}

extern "C" void kernel_launch(void* const* d_in, const int* in_sizes, int n_in,
                              void* d_out, int out_size, void* d_ws, size_t ws_size,
                              hipStream_t stream) {
    const float* x = (const float*)d_in[0];
    const float* w = (const float*)d_in[1];
    float* out = (float*)d_out;
    unsigned short* wt = (unsigned short*)d_ws;   // 344064 bf16 = 688 KB, L2-resident

    hipLaunchKernelGGL(prep_weights, dim3(1344), dim3(256), 0, stream, w, wt);
    // dynamic LDS = max over segs = seg0's 32*520*2 = 33280 B
    hipLaunchKernelGGL(fused_gemm, dim3(2560), dim3(512), 33280, stream, x, wt, out);
}